// Round 6
// baseline (1864.693 us; speedup 1.0000x reference)
//
#include <hip/hip_runtime.h>
#include <hip/hip_bf16.h>

// CGCNN forward, MI355X. R5: R4 + pair-permuted WT so pass A's z stores fully
// cover 64B sectors per instruction (R4 scattered 2B stores caused 707MB vs
// 400MB ideal WRITE_SIZE).
//   prep: CSR build (deg/scan/scatter), ef16 gathered into CSR order (48-pad)
//   3x: pass A (CSR order): z = [x[i1]|x[i2]|ef] @ Wf[l] (f16 MFMA, fp32 acc;
//         bf cancels in train-mode BN) + column sum/sumsq + store z pairs
//       pass B: wave-per-node: read contiguous zp run -> BN -> sig*softplus ->
//         register reduce -> ONE plain store per node (no atomics) + node stats
//       node apply: BN2 -> softplus -> new x (last layer also crystal atomics)
//   crystal seg-mean -> softplus(@Wc+bc) -> @Wo+bo

#define NN 100000
#define NE 1600000
#define NC 2000
#define KPAD 176
#define EFW 48
#define EPSB 1e-5f
#define NCH 1000
#define CH 100

typedef _Float16 f16;
typedef _Float16 half8 __attribute__((ext_vector_type(8)));
typedef _Float16 half2v __attribute__((ext_vector_type(2)));
typedef float f32x16 __attribute__((ext_vector_type(16)));

__device__ __forceinline__ f32x16 zero16() {
    f32x16 v;
#pragma unroll
    for (int i = 0; i < 16; i++) v[i] = 0.f;
    return v;
}
__device__ __forceinline__ float fsoftplus(float x) {
    return fmaxf(x, 0.f) + __logf(1.f + __expf(-fabsf(x)));
}
__device__ __forceinline__ float fsigmoid(float x) {
    return __fdividef(1.f, 1.f + __expf(-x));
}

// ---------- prep ----------
__global__ void k_prep_x(const int* __restrict__ nf, const float* __restrict__ emb,
                         float* __restrict__ xf, f16* __restrict__ x16) {
    for (int idx = blockIdx.x * blockDim.x + threadIdx.x; idx < NN * 64;
         idx += gridDim.x * blockDim.x) {
        int n = idx >> 6, k = idx & 63;
        float v = emb[nf[n] * 64 + k];
        xf[idx] = v;
        x16[idx] = (f16)v;
    }
}

__global__ void k_deg(const int* __restrict__ idx1, const int* __restrict__ idx3,
                      int* deg1, float* cnt3) {
    for (int i = blockIdx.x * blockDim.x + threadIdx.x; i < NE;
         i += gridDim.x * blockDim.x) {
        atomicAdd(&deg1[idx1[i]], 1);
        if (i < NN) atomicAdd(&cnt3[idx3[i]], 1.f);
    }
}

// exclusive prefix sum of deg -> rp (NCH chunks of CH)
__global__ void k_scan_a(const int* __restrict__ deg, int* __restrict__ csum) {
    int t = blockIdx.x * blockDim.x + threadIdx.x;
    if (t < NCH) {
        int s = 0;
        int base = t * CH;
        for (int i = 0; i < CH; i++) s += deg[base + i];
        csum[t] = s;
    }
}
__global__ void k_scan_b(const int* __restrict__ csum, int* __restrict__ coff) {
    __shared__ int sc[256];
    int t = threadIdx.x;
    int v[4];
    int part = 0;
#pragma unroll
    for (int q = 0; q < 4; q++) {
        int idx = 4 * t + q;
        v[q] = (idx < NCH) ? csum[idx] : 0;
        part += v[q];
    }
    sc[t] = part;
    __syncthreads();
    for (int off = 1; off < 256; off <<= 1) {
        int add = (t >= off) ? sc[t - off] : 0;
        __syncthreads();
        sc[t] += add;
        __syncthreads();
    }
    int run = sc[t] - part;  // exclusive
#pragma unroll
    for (int q = 0; q < 4; q++) {
        int idx = 4 * t + q;
        if (idx < NCH) coff[idx] = run;
        run += v[q];
    }
}
__global__ void k_scan_c(const int* __restrict__ deg, const int* __restrict__ coff,
                         int* __restrict__ rp) {
    int t = blockIdx.x * blockDim.x + threadIdx.x;
    if (t < NCH) {
        int running = coff[t];
        int base = t * CH;
        for (int i = 0; i < CH; i++) {
            rp[base + i] = running;
            running += deg[base + i];
        }
    }
}

__global__ void k_scatter(const int* __restrict__ idx1, const int* __restrict__ idx2,
                          const int* __restrict__ rp1, int* cur1, int* elist1,
                          int* i1r, int* i2r) {
    for (int e = blockIdx.x * blockDim.x + threadIdx.x; e < NE;
         e += gridDim.x * blockDim.x) {
        int n1 = idx1[e];
        int p = rp1[n1] + atomicAdd(&cur1[n1], 1);
        elist1[p] = e;
        i1r[p] = n1;
        i2r[p] = idx2[e];
    }
}

// ef16p[p][0:48] = pad48(edge_fea[elist1[p]])  (CSR-permuted, f16)
__global__ void k_prep_efg(const float* __restrict__ ef, const int* __restrict__ elist1,
                           f16* __restrict__ ef16p) {
    for (long idx = (long)blockIdx.x * blockDim.x + threadIdx.x; idx < (long)NE * EFW;
         idx += (long)gridDim.x * blockDim.x) {
        long p = idx / EFW;
        int k = (int)(idx - p * EFW);
        int e = elist1[p];
        float v = (k < 41) ? ef[(size_t)e * 41 + k] : 0.f;
        ef16p[idx] = (f16)v;
    }
}

// WTp[slot][k] = Wf_l[k][col(slot)], f16, k padded 169->176.
// slot = 32*q + cl: cl<16 -> gate col 16q+cl ; cl>=16 -> conv col 64+16q+(cl&15)
__global__ void k_wt(const float* __restrict__ Wf_l, f16* __restrict__ WTp) {
    for (int idx = blockIdx.x * blockDim.x + threadIdx.x; idx < 128 * KPAD;
         idx += gridDim.x * blockDim.x) {
        int sl = idx / KPAD, k = idx % KPAD;
        int q = sl >> 5, cl = sl & 31;
        int col = (cl & 16) ? 64 + q * 16 + (cl & 15) : q * 16 + cl;
        float v = (k < 169) ? Wf_l[k * 128 + col] : 0.f;
        WTp[idx] = (f16)v;
    }
}

// ---------- pass A: CSR-ordered GEMM + stats + z store ----------
// Block = 4 waves sharing one 32-edge tile; wave q owns col-slots 32q..32q+31
// (pair-permuted: 16 gate+16 conv cols forming pairs j=16q+0..15).
// Store: lane (c<16) writes gate half at byte 4j, lane (c>=16) conv at 4j+2
// -> each half-wave fully covers 64 contiguous bytes per instruction.
__global__ __launch_bounds__(256) void k_edge_a(
    const f16* __restrict__ x16, const f16* __restrict__ ef16p,
    const f16* __restrict__ WTp, const int* __restrict__ i1r,
    const int* __restrict__ i2r, float* __restrict__ estats,
    f16* __restrict__ zph) {
    __shared__ float lst[256];
    int tid = threadIdx.x;
    int lane = tid & 63;
    int q = tid >> 6;
    int c = lane & 31, kg = lane >> 5;
    int slot = 32 * q + c;
    // actual z column this lane produces:
    int jz = (c & 16) ? 64 + q * 16 + (c & 15) : q * 16 + c;

    half8 bfr[11];
    {
        const f16* bp = WTp + slot * KPAD + kg * 8;
#pragma unroll
        for (int s = 0; s < 11; s++)
            bfr[s] = *reinterpret_cast<const half8*>(bp + s * 16);
    }
    // z pair layout consumed by k_nodered: {gate j, conv j} f16s at p*128+2j
    const size_t zoff = 2 * (size_t)(q * 16 + (c & 15)) + ((c >> 4) & 1);

    float s1 = 0.f, s2 = 0.f;
    const int NT = NE / 32;
    for (int tile = blockIdx.x; tile < NT; tile += gridDim.x) {
        int p0 = tile * 32;
        long p = p0 + c;
        int i1 = i1r[p], i2 = i2r[p];
        f32x16 acc = zero16();
#pragma unroll
        for (int s = 0; s < 4; s++) {
            half8 a = *reinterpret_cast<const half8*>(x16 + (size_t)i1 * 64 + s * 16 + kg * 8);
            acc = __builtin_amdgcn_mfma_f32_32x32x16_f16(a, bfr[s], acc, 0, 0, 0);
        }
#pragma unroll
        for (int s = 0; s < 4; s++) {
            half8 a = *reinterpret_cast<const half8*>(x16 + (size_t)i2 * 64 + s * 16 + kg * 8);
            acc = __builtin_amdgcn_mfma_f32_32x32x16_f16(a, bfr[4 + s], acc, 0, 0, 0);
        }
#pragma unroll
        for (int s = 0; s < 3; s++) {
            half8 a = *reinterpret_cast<const half8*>(ef16p + p * EFW + s * 16 + kg * 8);
            acc = __builtin_amdgcn_mfma_f32_32x32x16_f16(a, bfr[8 + s], acc, 0, 0, 0);
        }
#pragma unroll
        for (int r = 0; r < 16; r++) {
            float v = acc[r];
            s1 += v;
            s2 += v * v;
            int row = (r & 3) + 8 * (r >> 2) + 4 * kg;
            zph[(size_t)(p0 + row) * 128 + zoff] = (f16)v;
        }
    }
    s1 += __shfl_xor(s1, 32, 64);
    s2 += __shfl_xor(s2, 32, 64);
    if (kg == 0) {
        lst[jz] = s1;         // each actual column written by exactly one lane
        lst[128 + jz] = s2;
    }
    __syncthreads();
    atomicAdd(&estats[tid], lst[tid]);
}

// ---------- pass B: wave-per-node reduce (no atomics on nodesum) ----------
__global__ __launch_bounds__(256) void k_nodered(
    const half2v* __restrict__ zp, const int* __restrict__ rp1,
    const int* __restrict__ deg1, const float* __restrict__ estats,
    const float* __restrict__ g1, const float* __restrict__ be1,
    float* __restrict__ raw_out, float* __restrict__ nstats) {
    __shared__ float sstat[128];
    int tid = threadIdx.x;
    int j = tid & 63, wv = tid >> 6;
    if (tid < 128) sstat[tid] = 0.f;
    __syncthreads();
    float mg = estats[j] * (1.f / NE);
    float vg = estats[128 + j] * (1.f / NE) - mg * mg;
    float ag = g1[j] * rsqrtf(vg + EPSB);
    float bg = be1[j] - mg * ag;
    float mc = estats[64 + j] * (1.f / NE);
    float vc = estats[192 + j] * (1.f / NE) - mc * mc;
    float ac = g1[64 + j] * rsqrtf(vc + EPSB);
    float bc = be1[64 + j] - mc * ac;
    float p1 = 0.f, p2 = 0.f;
    for (int n = blockIdx.x * 4 + wv; n < NN; n += gridDim.x * 4) {
        int st = rp1[n], d = deg1[n];
        float acc = 0.f;
#pragma unroll 4
        for (int q = 0; q < d; q++) {
            half2v z = __builtin_nontemporal_load(&zp[(size_t)(st + q) * 64 + j]);
            float g = fsigmoid((float)z[0] * ag + bg);
            float s = fsoftplus((float)z[1] * ac + bc);
            acc += g * s;
        }
        float raw = acc / fmaxf((float)d, 1.f);
        raw_out[(size_t)n * 64 + j] = raw;
        p1 += raw;
        p2 += raw * raw;
    }
    atomicAdd(&sstat[j], p1);
    atomicAdd(&sstat[64 + j], p2);
    __syncthreads();
    if (tid < 128) atomicAdd(&nstats[tid], sstat[tid]);
}

// ---------- node apply: BN2 + softplus (+ crystal pool on last layer) ----------
template <bool LAST>
__global__ __launch_bounds__(256) void k_node_apply(
    const float* __restrict__ raw_in, const float* __restrict__ nstats,
    const float* __restrict__ g2, const float* __restrict__ be2,
    float* __restrict__ xf, f16* __restrict__ x16, const int* __restrict__ idx3,
    float* __restrict__ crsum) {
    for (int idx = blockIdx.x * blockDim.x + threadIdx.x; idx < NN * 64;
         idx += gridDim.x * blockDim.x) {
        int n = idx >> 6, j = idx & 63;
        float m = nstats[j] * (1.f / NN);
        float var = nstats[64 + j] * (1.f / NN) - m * m;
        float rs = rsqrtf(var + EPSB);
        float a = g2[j] * rs;
        float b = be2[j] - m * a;
        float v = fsoftplus(xf[idx] + raw_in[idx] * a + b);
        if (LAST) {
            atomicAdd(&crsum[(size_t)idx3[n] * 64 + j], v);
        } else {
            xf[idx] = v;
            x16[idx] = (f16)v;
        }
    }
}

// ---------- output MLP ----------
__global__ __launch_bounds__(128) void k_out(const float* __restrict__ crsum,
                                             const float* __restrict__ cnt3,
                                             const float* __restrict__ Wc,
                                             const float* __restrict__ bcv,
                                             const float* __restrict__ Wo,
                                             const float* __restrict__ bo,
                                             float* __restrict__ out) {
    __shared__ float crym[64];
    __shared__ float red[4];
    int c = blockIdx.x, tid = threadIdx.x;
    if (tid < 64) crym[tid] = crsum[c * 64 + tid] / fmaxf(cnt3[c], 1.f);
    __syncthreads();
    float hv = bcv[tid];
#pragma unroll
    for (int k = 0; k < 64; k++) hv += crym[k] * Wc[k * 128 + tid];
    hv = fsoftplus(hv);
    float o0 = hv * Wo[tid * 2 + 0];
    float o1 = hv * Wo[tid * 2 + 1];
#pragma unroll
    for (int off = 32; off > 0; off >>= 1) {
        o0 += __shfl_down(o0, off, 64);
        o1 += __shfl_down(o1, off, 64);
    }
    int wv = tid >> 6;
    if ((tid & 63) == 0) { red[wv * 2] = o0; red[wv * 2 + 1] = o1; }
    __syncthreads();
    if (tid == 0) {
        out[c * 2 + 0] = red[0] + red[2] + bo[0];
        out[c * 2 + 1] = red[1] + red[3] + bo[1];
    }
}

// ---------- launch ----------
static inline size_t al256(size_t x) { return (x + 255) & ~(size_t)255; }

extern "C" void kernel_launch(void* const* d_in, const int* in_sizes, int n_in,
                              void* d_out, int out_size, void* d_ws, size_t ws_size,
                              hipStream_t stream) {
    const int* node_fea = (const int*)d_in[0];
    const float* edge_fea = (const float*)d_in[1];
    const int* idx1 = (const int*)d_in[2];
    const int* idx2 = (const int*)d_in[3];
    const int* idx3 = (const int*)d_in[4];
    const float* emb = (const float*)d_in[5];
    const float* Wf = (const float*)d_in[6];
    // d_in[7] = bf: cancels inside training-mode BN, unused.
    const float* g1 = (const float*)d_in[8];
    const float* be1 = (const float*)d_in[9];
    const float* g2 = (const float*)d_in[10];
    const float* be2 = (const float*)d_in[11];
    const float* Wc = (const float*)d_in[12];
    const float* bc = (const float*)d_in[13];
    const float* Wo = (const float*)d_in[14];
    const float* bo = (const float*)d_in[15];
    float* out = (float*)d_out;
    unsigned char* ws = (unsigned char*)d_ws;

    size_t off = 0;
    size_t o_xf = off;     off = al256(off + (size_t)NN * 64 * 4);
    size_t o_x16 = off;    off = al256(off + (size_t)NN * 64 * 2);
    size_t o_efp = off;    off = al256(off + (size_t)NE * EFW * 2);
    size_t o_WT = off;     off = al256(off + (size_t)128 * KPAD * 2);
    size_t o_rp1 = off;    off = al256(off + (size_t)NN * 4);
    size_t o_el1 = off;    off = al256(off + (size_t)NE * 4);
    size_t o_i1r = off;    off = al256(off + (size_t)NE * 4);
    size_t o_i2r = off;    off = al256(off + (size_t)NE * 4);
    size_t o_raw = off;    off = al256(off + (size_t)NN * 64 * 4);
    // prep-zero region (one memset):
    size_t o_deg1 = off;   off = al256(off + (size_t)NN * 4);
    size_t o_cur1 = off;   off = al256(off + (size_t)NN * 4);
    size_t o_cnt3 = off;   off = al256(off + (size_t)NC * 4);
    size_t o_csum = off;   off = al256(off + 1024 * 4);
    size_t o_coff = off;   off = al256(off + 1024 * 4);
    size_t o_crsum = off;  off = al256(off + (size_t)NC * 64 * 4);
    size_t prep_zero_end = off;
    // per-layer-zero region (tiny memset per layer):
    size_t o_estats = off; off = al256(off + 256 * 4);
    size_t o_nstats = off; off = al256(off + 128 * 4);
    size_t layer_zero_end = off;
    size_t o_z = off;      off = al256(off + (size_t)NE * 64 * 4);
    (void)ws_size;

    float* xf = (float*)(ws + o_xf);
    f16* x16 = (f16*)(ws + o_x16);
    f16* ef16p = (f16*)(ws + o_efp);
    f16* WTp = (f16*)(ws + o_WT);
    int* rp1 = (int*)(ws + o_rp1);
    int* elist1 = (int*)(ws + o_el1);
    int* i1r = (int*)(ws + o_i1r);
    int* i2r = (int*)(ws + o_i2r);
    float* raw = (float*)(ws + o_raw);
    int* deg1 = (int*)(ws + o_deg1);
    int* cur1 = (int*)(ws + o_cur1);
    float* cnt3 = (float*)(ws + o_cnt3);
    int* csum = (int*)(ws + o_csum);
    int* coff = (int*)(ws + o_coff);
    float* crsum = (float*)(ws + o_crsum);
    float* estats = (float*)(ws + o_estats);
    float* nstats = (float*)(ws + o_nstats);
    f16* zph = (f16*)(ws + o_z);
    half2v* zp = (half2v*)(ws + o_z);

    hipMemsetAsync(ws + o_deg1, 0, prep_zero_end - o_deg1, stream);
    k_prep_x<<<1024, 256, 0, stream>>>(node_fea, emb, xf, x16);
    k_deg<<<2048, 256, 0, stream>>>(idx1, idx3, deg1, cnt3);
    k_scan_a<<<4, 256, 0, stream>>>(deg1, csum);
    k_scan_b<<<1, 256, 0, stream>>>(csum, coff);
    k_scan_c<<<4, 256, 0, stream>>>(deg1, coff, rp1);
    k_scatter<<<2048, 256, 0, stream>>>(idx1, idx2, rp1, cur1, elist1, i1r, i2r);
    k_prep_efg<<<4096, 256, 0, stream>>>(edge_fea, elist1, ef16p);

    for (int l = 0; l < 3; l++) {
        const float* Wf_l = Wf + (size_t)l * 169 * 128;
        hipMemsetAsync(ws + o_estats, 0, layer_zero_end - o_estats, stream);
        k_wt<<<88, 256, 0, stream>>>(Wf_l, WTp);
        k_edge_a<<<4096, 256, 0, stream>>>(x16, ef16p, WTp, i1r, i2r, estats, zph);
        k_nodered<<<4096, 256, 0, stream>>>(zp, rp1, deg1, estats, g1 + l * 128,
                                            be1 + l * 128, raw, nstats);
        if (l < 2) {
            k_node_apply<false><<<1024, 256, 0, stream>>>(raw, nstats, g2 + l * 64,
                                                          be2 + l * 64, xf, x16,
                                                          idx3, crsum);
        } else {
            k_node_apply<true><<<1024, 256, 0, stream>>>(raw, nstats, g2 + l * 64,
                                                         be2 + l * 64, xf, x16,
                                                         idx3, crsum);
        }
    }
    k_out<<<2000, 128, 0, stream>>>(crsum, cnt3, Wc, bc, Wo, bo, out);
}

// Round 7
// 1828.017 us; speedup vs baseline: 1.0201x; 1.0201x over previous
//
#include <hip/hip_runtime.h>
#include <hip/hip_bf16.h>

// CGCNN forward, MI355X. R6: R5 + LDS-shared, prefetched x16[i2] gather in
// pass A (the only divergent-address load; i1 is CSR-sorted -> L1, ef16p is
// sequential). Wave q stages seg q of next tile's i2 frags into dbuf LDS;
// divergent gathers drop 16->4 per tile and hide under current-tile compute.
//   prep: CSR build (deg/scan/scatter), ef16 gathered into CSR order (48-pad)
//   3x: pass A (CSR order): z = [x[i1]|x[i2]|ef] @ Wf[l] (f16 MFMA, fp32 acc;
//         bf cancels in train-mode BN) + column sum/sumsq + store z pairs
//       pass B: wave-per-node: read contiguous zp run -> BN -> sig*softplus ->
//         register reduce -> ONE plain store per node (no atomics) + node stats
//       node apply: BN2 -> softplus -> new x (last layer also crystal atomics)
//   crystal seg-mean -> softplus(@Wc+bc) -> @Wo+bo

#define NN 100000
#define NE 1600000
#define NC 2000
#define KPAD 176
#define EFW 48
#define EPSB 1e-5f
#define NCH 1000
#define CH 100

typedef _Float16 f16;
typedef _Float16 half8 __attribute__((ext_vector_type(8)));
typedef _Float16 half2v __attribute__((ext_vector_type(2)));
typedef float f32x16 __attribute__((ext_vector_type(16)));

__device__ __forceinline__ f32x16 zero16() {
    f32x16 v;
#pragma unroll
    for (int i = 0; i < 16; i++) v[i] = 0.f;
    return v;
}
__device__ __forceinline__ float fsoftplus(float x) {
    return fmaxf(x, 0.f) + __logf(1.f + __expf(-fabsf(x)));
}
__device__ __forceinline__ float fsigmoid(float x) {
    return __fdividef(1.f, 1.f + __expf(-x));
}

// ---------- prep ----------
__global__ void k_prep_x(const int* __restrict__ nf, const float* __restrict__ emb,
                         float* __restrict__ xf, f16* __restrict__ x16) {
    for (int idx = blockIdx.x * blockDim.x + threadIdx.x; idx < NN * 64;
         idx += gridDim.x * blockDim.x) {
        int n = idx >> 6, k = idx & 63;
        float v = emb[nf[n] * 64 + k];
        xf[idx] = v;
        x16[idx] = (f16)v;
    }
}

__global__ void k_deg(const int* __restrict__ idx1, const int* __restrict__ idx3,
                      int* deg1, float* cnt3) {
    for (int i = blockIdx.x * blockDim.x + threadIdx.x; i < NE;
         i += gridDim.x * blockDim.x) {
        atomicAdd(&deg1[idx1[i]], 1);
        if (i < NN) atomicAdd(&cnt3[idx3[i]], 1.f);
    }
}

// exclusive prefix sum of deg -> rp (NCH chunks of CH)
__global__ void k_scan_a(const int* __restrict__ deg, int* __restrict__ csum) {
    int t = blockIdx.x * blockDim.x + threadIdx.x;
    if (t < NCH) {
        int s = 0;
        int base = t * CH;
        for (int i = 0; i < CH; i++) s += deg[base + i];
        csum[t] = s;
    }
}
__global__ void k_scan_b(const int* __restrict__ csum, int* __restrict__ coff) {
    __shared__ int sc[256];
    int t = threadIdx.x;
    int v[4];
    int part = 0;
#pragma unroll
    for (int q = 0; q < 4; q++) {
        int idx = 4 * t + q;
        v[q] = (idx < NCH) ? csum[idx] : 0;
        part += v[q];
    }
    sc[t] = part;
    __syncthreads();
    for (int off = 1; off < 256; off <<= 1) {
        int add = (t >= off) ? sc[t - off] : 0;
        __syncthreads();
        sc[t] += add;
        __syncthreads();
    }
    int run = sc[t] - part;  // exclusive
#pragma unroll
    for (int q = 0; q < 4; q++) {
        int idx = 4 * t + q;
        if (idx < NCH) coff[idx] = run;
        run += v[q];
    }
}
__global__ void k_scan_c(const int* __restrict__ deg, const int* __restrict__ coff,
                         int* __restrict__ rp) {
    int t = blockIdx.x * blockDim.x + threadIdx.x;
    if (t < NCH) {
        int running = coff[t];
        int base = t * CH;
        for (int i = 0; i < CH; i++) {
            rp[base + i] = running;
            running += deg[base + i];
        }
    }
}

__global__ void k_scatter(const int* __restrict__ idx1, const int* __restrict__ idx2,
                          const int* __restrict__ rp1, int* cur1, int* elist1,
                          int* i1r, int* i2r) {
    for (int e = blockIdx.x * blockDim.x + threadIdx.x; e < NE;
         e += gridDim.x * blockDim.x) {
        int n1 = idx1[e];
        int p = rp1[n1] + atomicAdd(&cur1[n1], 1);
        elist1[p] = e;
        i1r[p] = n1;
        i2r[p] = idx2[e];
    }
}

// ef16p[p][0:48] = pad48(edge_fea[elist1[p]])  (CSR-permuted, f16)
__global__ void k_prep_efg(const float* __restrict__ ef, const int* __restrict__ elist1,
                           f16* __restrict__ ef16p) {
    for (long idx = (long)blockIdx.x * blockDim.x + threadIdx.x; idx < (long)NE * EFW;
         idx += (long)gridDim.x * blockDim.x) {
        long p = idx / EFW;
        int k = (int)(idx - p * EFW);
        int e = elist1[p];
        float v = (k < 41) ? ef[(size_t)e * 41 + k] : 0.f;
        ef16p[idx] = (f16)v;
    }
}

// WTp[slot][k] = Wf_l[k][col(slot)], f16, k padded 169->176.
// slot = 32*q + cl: cl<16 -> gate col 16q+cl ; cl>=16 -> conv col 64+16q+(cl&15)
__global__ void k_wt(const float* __restrict__ Wf_l, f16* __restrict__ WTp) {
    for (int idx = blockIdx.x * blockDim.x + threadIdx.x; idx < 128 * KPAD;
         idx += gridDim.x * blockDim.x) {
        int sl = idx / KPAD, k = idx % KPAD;
        int q = sl >> 5, cl = sl & 31;
        int col = (cl & 16) ? 64 + q * 16 + (cl & 15) : q * 16 + cl;
        float v = (k < 169) ? Wf_l[k * 128 + col] : 0.f;
        WTp[idx] = (f16)v;
    }
}

// ---------- pass A: CSR-ordered GEMM + stats + z store ----------
// Block = 4 waves sharing one 32-edge tile; wave q owns col-slots 32q..32q+31
// (pair-permuted). x16[i2] frags (the only random gather) are staged in
// double-buffered LDS: wave q gathers seg q of tile t+1 (1 instr/wave/tile),
// issued before tile t's compute so latency hides under MFMA+epilogue.
__global__ __launch_bounds__(256) void k_edge_a(
    const f16* __restrict__ x16, const f16* __restrict__ ef16p,
    const f16* __restrict__ WTp, const int* __restrict__ i1r,
    const int* __restrict__ i2r, float* __restrict__ estats,
    f16* __restrict__ zph) {
    __shared__ float lst[256];
    __shared__ f16 abuf[2][4][2][32][8];  // [dbuf][seg][kg][edge][8 f16]
    int tid = threadIdx.x;
    int lane = tid & 63;
    int q = tid >> 6;
    int c = lane & 31, kg = lane >> 5;
    int slot = 32 * q + c;
    // actual z column this lane produces:
    int jz = (c & 16) ? 64 + q * 16 + (c & 15) : q * 16 + c;

    half8 bfr[11];
    {
        const f16* bp = WTp + slot * KPAD + kg * 8;
#pragma unroll
        for (int s = 0; s < 11; s++)
            bfr[s] = *reinterpret_cast<const half8*>(bp + s * 16);
    }
    // z pair layout consumed by k_nodered: {gate j, conv j} f16s at p*128+2j
    const size_t zoff = 2 * (size_t)(q * 16 + (c & 15)) + ((c >> 4) & 1);

    float s1 = 0.f, s2 = 0.f;
    const int NT = NE / 32;
    const int stride = gridDim.x;
    int t = blockIdx.x;  // grid (4096) < NT (50000): every block has >=1 tile
    // prologue: stage tile t's i2 seg-q fragments into buf 0
    int i1v = i1r[(size_t)t * 32 + c];
    int i2v = i2r[(size_t)t * 32 + c];
    *reinterpret_cast<half8*>(&abuf[0][q][kg][c][0]) =
        *reinterpret_cast<const half8*>(x16 + (size_t)i2v * 64 + q * 16 + kg * 8);
    __syncthreads();
    int cur = 0;
    for (; t < NT; t += stride) {
        int tn = t + stride;
        bool hasn = (tn < NT);
        int i1n = 0, i2n = 0;
        half8 gn;
        if (hasn) {  // issue next tile's gather early (latency hides below)
            i1n = i1r[(size_t)tn * 32 + c];
            i2n = i2r[(size_t)tn * 32 + c];
            gn = *reinterpret_cast<const half8*>(x16 + (size_t)i2n * 64 + q * 16 + kg * 8);
        }
        int p0 = t * 32;
        long p = p0 + c;
        f32x16 acc = zero16();
#pragma unroll
        for (int s = 0; s < 4; s++) {  // i1 frags: CSR-sorted -> L1 hits
            half8 a = *reinterpret_cast<const half8*>(x16 + (size_t)i1v * 64 + s * 16 + kg * 8);
            acc = __builtin_amdgcn_mfma_f32_32x32x16_f16(a, bfr[s], acc, 0, 0, 0);
        }
#pragma unroll
        for (int s = 0; s < 4; s++) {  // i2 frags: from LDS (staged last iter)
            half8 a = *reinterpret_cast<const half8*>(&abuf[cur][s][kg][c][0]);
            acc = __builtin_amdgcn_mfma_f32_32x32x16_f16(a, bfr[4 + s], acc, 0, 0, 0);
        }
#pragma unroll
        for (int s = 0; s < 3; s++) {  // ef frags: sequential stream
            half8 a = *reinterpret_cast<const half8*>(ef16p + p * EFW + s * 16 + kg * 8);
            acc = __builtin_amdgcn_mfma_f32_32x32x16_f16(a, bfr[8 + s], acc, 0, 0, 0);
        }
#pragma unroll
        for (int r = 0; r < 16; r++) {
            float v = acc[r];
            s1 += v;
            s2 += v * v;
            int row = (r & 3) + 8 * (r >> 2) + 4 * kg;
            zph[(size_t)(p0 + row) * 128 + zoff] = (f16)v;
        }
        if (hasn) {  // park next tile's frags in the other buffer
            *reinterpret_cast<half8*>(&abuf[cur ^ 1][q][kg][c][0]) = gn;
            i1v = i1n;
            i2v = i2n;
        }
        __syncthreads();  // ds_write visible to all; buf[cur] reads done
        cur ^= 1;
    }
    s1 += __shfl_xor(s1, 32, 64);
    s2 += __shfl_xor(s2, 32, 64);
    if (kg == 0) {
        lst[jz] = s1;  // each actual column written by exactly one lane
        lst[128 + jz] = s2;
    }
    __syncthreads();
    atomicAdd(&estats[tid], lst[tid]);
}

// ---------- pass B: wave-per-node reduce (no atomics on nodesum) ----------
__global__ __launch_bounds__(256) void k_nodered(
    const half2v* __restrict__ zp, const int* __restrict__ rp1,
    const int* __restrict__ deg1, const float* __restrict__ estats,
    const float* __restrict__ g1, const float* __restrict__ be1,
    float* __restrict__ raw_out, float* __restrict__ nstats) {
    __shared__ float sstat[128];
    int tid = threadIdx.x;
    int j = tid & 63, wv = tid >> 6;
    if (tid < 128) sstat[tid] = 0.f;
    __syncthreads();
    float mg = estats[j] * (1.f / NE);
    float vg = estats[128 + j] * (1.f / NE) - mg * mg;
    float ag = g1[j] * rsqrtf(vg + EPSB);
    float bg = be1[j] - mg * ag;
    float mc = estats[64 + j] * (1.f / NE);
    float vc = estats[192 + j] * (1.f / NE) - mc * mc;
    float ac = g1[64 + j] * rsqrtf(vc + EPSB);
    float bc = be1[64 + j] - mc * ac;
    float p1 = 0.f, p2 = 0.f;
    for (int n = blockIdx.x * 4 + wv; n < NN; n += gridDim.x * 4) {
        int st = rp1[n], d = deg1[n];
        float acc = 0.f;
#pragma unroll 4
        for (int q = 0; q < d; q++) {
            half2v z = __builtin_nontemporal_load(&zp[(size_t)(st + q) * 64 + j]);
            float g = fsigmoid((float)z[0] * ag + bg);
            float s = fsoftplus((float)z[1] * ac + bc);
            acc += g * s;
        }
        float raw = acc / fmaxf((float)d, 1.f);
        raw_out[(size_t)n * 64 + j] = raw;
        p1 += raw;
        p2 += raw * raw;
    }
    atomicAdd(&sstat[j], p1);
    atomicAdd(&sstat[64 + j], p2);
    __syncthreads();
    if (tid < 128) atomicAdd(&nstats[tid], sstat[tid]);
}

// ---------- node apply: BN2 + softplus (+ crystal pool on last layer) ----------
template <bool LAST>
__global__ __launch_bounds__(256) void k_node_apply(
    const float* __restrict__ raw_in, const float* __restrict__ nstats,
    const float* __restrict__ g2, const float* __restrict__ be2,
    float* __restrict__ xf, f16* __restrict__ x16, const int* __restrict__ idx3,
    float* __restrict__ crsum) {
    for (int idx = blockIdx.x * blockDim.x + threadIdx.x; idx < NN * 64;
         idx += gridDim.x * blockDim.x) {
        int n = idx >> 6, j = idx & 63;
        float m = nstats[j] * (1.f / NN);
        float var = nstats[64 + j] * (1.f / NN) - m * m;
        float rs = rsqrtf(var + EPSB);
        float a = g2[j] * rs;
        float b = be2[j] - m * a;
        float v = fsoftplus(xf[idx] + raw_in[idx] * a + b);
        if (LAST) {
            atomicAdd(&crsum[(size_t)idx3[n] * 64 + j], v);
        } else {
            xf[idx] = v;
            x16[idx] = (f16)v;
        }
    }
}

// ---------- output MLP ----------
__global__ __launch_bounds__(128) void k_out(const float* __restrict__ crsum,
                                             const float* __restrict__ cnt3,
                                             const float* __restrict__ Wc,
                                             const float* __restrict__ bcv,
                                             const float* __restrict__ Wo,
                                             const float* __restrict__ bo,
                                             float* __restrict__ out) {
    __shared__ float crym[64];
    __shared__ float red[4];
    int c = blockIdx.x, tid = threadIdx.x;
    if (tid < 64) crym[tid] = crsum[c * 64 + tid] / fmaxf(cnt3[c], 1.f);
    __syncthreads();
    float hv = bcv[tid];
#pragma unroll
    for (int k = 0; k < 64; k++) hv += crym[k] * Wc[k * 128 + tid];
    hv = fsoftplus(hv);
    float o0 = hv * Wo[tid * 2 + 0];
    float o1 = hv * Wo[tid * 2 + 1];
#pragma unroll
    for (int off = 32; off > 0; off >>= 1) {
        o0 += __shfl_down(o0, off, 64);
        o1 += __shfl_down(o1, off, 64);
    }
    int wv = tid >> 6;
    if ((tid & 63) == 0) { red[wv * 2] = o0; red[wv * 2 + 1] = o1; }
    __syncthreads();
    if (tid == 0) {
        out[c * 2 + 0] = red[0] + red[2] + bo[0];
        out[c * 2 + 1] = red[1] + red[3] + bo[1];
    }
}

// ---------- launch ----------
static inline size_t al256(size_t x) { return (x + 255) & ~(size_t)255; }

extern "C" void kernel_launch(void* const* d_in, const int* in_sizes, int n_in,
                              void* d_out, int out_size, void* d_ws, size_t ws_size,
                              hipStream_t stream) {
    const int* node_fea = (const int*)d_in[0];
    const float* edge_fea = (const float*)d_in[1];
    const int* idx1 = (const int*)d_in[2];
    const int* idx2 = (const int*)d_in[3];
    const int* idx3 = (const int*)d_in[4];
    const float* emb = (const float*)d_in[5];
    const float* Wf = (const float*)d_in[6];
    // d_in[7] = bf: cancels inside training-mode BN, unused.
    const float* g1 = (const float*)d_in[8];
    const float* be1 = (const float*)d_in[9];
    const float* g2 = (const float*)d_in[10];
    const float* be2 = (const float*)d_in[11];
    const float* Wc = (const float*)d_in[12];
    const float* bc = (const float*)d_in[13];
    const float* Wo = (const float*)d_in[14];
    const float* bo = (const float*)d_in[15];
    float* out = (float*)d_out;
    unsigned char* ws = (unsigned char*)d_ws;

    size_t off = 0;
    size_t o_xf = off;     off = al256(off + (size_t)NN * 64 * 4);
    size_t o_x16 = off;    off = al256(off + (size_t)NN * 64 * 2);
    size_t o_efp = off;    off = al256(off + (size_t)NE * EFW * 2);
    size_t o_WT = off;     off = al256(off + (size_t)128 * KPAD * 2);
    size_t o_rp1 = off;    off = al256(off + (size_t)NN * 4);
    size_t o_el1 = off;    off = al256(off + (size_t)NE * 4);
    size_t o_i1r = off;    off = al256(off + (size_t)NE * 4);
    size_t o_i2r = off;    off = al256(off + (size_t)NE * 4);
    size_t o_raw = off;    off = al256(off + (size_t)NN * 64 * 4);
    // prep-zero region (one memset):
    size_t o_deg1 = off;   off = al256(off + (size_t)NN * 4);
    size_t o_cur1 = off;   off = al256(off + (size_t)NN * 4);
    size_t o_cnt3 = off;   off = al256(off + (size_t)NC * 4);
    size_t o_csum = off;   off = al256(off + 1024 * 4);
    size_t o_coff = off;   off = al256(off + 1024 * 4);
    size_t o_crsum = off;  off = al256(off + (size_t)NC * 64 * 4);
    size_t prep_zero_end = off;
    // per-layer-zero region (tiny memset per layer):
    size_t o_estats = off; off = al256(off + 256 * 4);
    size_t o_nstats = off; off = al256(off + 128 * 4);
    size_t layer_zero_end = off;
    size_t o_z = off;      off = al256(off + (size_t)NE * 64 * 4);
    (void)ws_size;

    float* xf = (float*)(ws + o_xf);
    f16* x16 = (f16*)(ws + o_x16);
    f16* ef16p = (f16*)(ws + o_efp);
    f16* WTp = (f16*)(ws + o_WT);
    int* rp1 = (int*)(ws + o_rp1);
    int* elist1 = (int*)(ws + o_el1);
    int* i1r = (int*)(ws + o_i1r);
    int* i2r = (int*)(ws + o_i2r);
    float* raw = (float*)(ws + o_raw);
    int* deg1 = (int*)(ws + o_deg1);
    int* cur1 = (int*)(ws + o_cur1);
    float* cnt3 = (float*)(ws + o_cnt3);
    int* csum = (int*)(ws + o_csum);
    int* coff = (int*)(ws + o_coff);
    float* crsum = (float*)(ws + o_crsum);
    float* estats = (float*)(ws + o_estats);
    float* nstats = (float*)(ws + o_nstats);
    f16* zph = (f16*)(ws + o_z);
    half2v* zp = (half2v*)(ws + o_z);

    hipMemsetAsync(ws + o_deg1, 0, prep_zero_end - o_deg1, stream);
    k_prep_x<<<1024, 256, 0, stream>>>(node_fea, emb, xf, x16);
    k_deg<<<2048, 256, 0, stream>>>(idx1, idx3, deg1, cnt3);
    k_scan_a<<<4, 256, 0, stream>>>(deg1, csum);
    k_scan_b<<<1, 256, 0, stream>>>(csum, coff);
    k_scan_c<<<4, 256, 0, stream>>>(deg1, coff, rp1);
    k_scatter<<<2048, 256, 0, stream>>>(idx1, idx2, rp1, cur1, elist1, i1r, i2r);
    k_prep_efg<<<4096, 256, 0, stream>>>(edge_fea, elist1, ef16p);

    for (int l = 0; l < 3; l++) {
        const float* Wf_l = Wf + (size_t)l * 169 * 128;
        hipMemsetAsync(ws + o_estats, 0, layer_zero_end - o_estats, stream);
        k_wt<<<88, 256, 0, stream>>>(Wf_l, WTp);
        k_edge_a<<<4096, 256, 0, stream>>>(x16, ef16p, WTp, i1r, i2r, estats, zph);
        k_nodered<<<4096, 256, 0, stream>>>(zp, rp1, deg1, estats, g1 + l * 128,
                                            be1 + l * 128, raw, nstats);
        if (l < 2) {
            k_node_apply<false><<<1024, 256, 0, stream>>>(raw, nstats, g2 + l * 64,
                                                          be2 + l * 64, xf, x16,
                                                          idx3, crsum);
        } else {
            k_node_apply<true><<<1024, 256, 0, stream>>>(raw, nstats, g2 + l * 64,
                                                         be2 + l * 64, xf, x16,
                                                         idx3, crsum);
        }
    }
    k_out<<<2000, 128, 0, stream>>>(crsum, cnt3, Wc, bc, Wo, bo, out);
}

// Round 8
// 1754.661 us; speedup vs baseline: 1.0627x; 1.0418x over previous
//
#include <hip/hip_runtime.h>
#include <hip/hip_bf16.h>

// CGCNN forward, MI355X. R7: pass A restructured — B (44KB) staged in LDS
// fragment-major (conflict-free ds_read_b128), ONE wave per 32-edge x 128-col
// tile (zero A redundancy, no per-tile barriers), full A-frag prefetch one
// tile ahead + indices two ahead.
//   prep: CSR build (deg/scan/scatter), ef16 gathered into CSR order (48-pad)
//   3x: pass A (CSR order): z = [x[i1]|x[i2]|ef] @ Wf[l] (f16 MFMA, fp32 acc;
//         bf cancels in train-mode BN) + column sum/sumsq + store z pairs
//       pass B: wave-per-node: read contiguous zp run -> BN -> sig*softplus ->
//         register reduce -> ONE plain store per node (no atomics) + node stats
//       node apply: BN2 -> softplus -> new x (last layer also crystal atomics)
//   crystal seg-mean -> softplus(@Wc+bc) -> @Wo+bo

#define NN 100000
#define NE 1600000
#define NC 2000
#define KPAD 176
#define NFRAG 11
#define EFW 48
#define EPSB 1e-5f
#define NCH 1000
#define CH 100

typedef _Float16 f16;
typedef _Float16 half8 __attribute__((ext_vector_type(8)));
typedef _Float16 half2v __attribute__((ext_vector_type(2)));
typedef float f32x16 __attribute__((ext_vector_type(16)));

__device__ __forceinline__ f32x16 zero16() {
    f32x16 v;
#pragma unroll
    for (int i = 0; i < 16; i++) v[i] = 0.f;
    return v;
}
__device__ __forceinline__ float fsoftplus(float x) {
    return fmaxf(x, 0.f) + __logf(1.f + __expf(-fabsf(x)));
}
__device__ __forceinline__ float fsigmoid(float x) {
    return __fdividef(1.f, 1.f + __expf(-x));
}

// ---------- prep ----------
__global__ void k_prep_x(const int* __restrict__ nf, const float* __restrict__ emb,
                         float* __restrict__ xf, f16* __restrict__ x16) {
    for (int idx = blockIdx.x * blockDim.x + threadIdx.x; idx < NN * 64;
         idx += gridDim.x * blockDim.x) {
        int n = idx >> 6, k = idx & 63;
        float v = emb[nf[n] * 64 + k];
        xf[idx] = v;
        x16[idx] = (f16)v;
    }
}

__global__ void k_deg(const int* __restrict__ idx1, const int* __restrict__ idx3,
                      int* deg1, float* cnt3) {
    for (int i = blockIdx.x * blockDim.x + threadIdx.x; i < NE;
         i += gridDim.x * blockDim.x) {
        atomicAdd(&deg1[idx1[i]], 1);
        if (i < NN) atomicAdd(&cnt3[idx3[i]], 1.f);
    }
}

// exclusive prefix sum of deg -> rp (NCH chunks of CH)
__global__ void k_scan_a(const int* __restrict__ deg, int* __restrict__ csum) {
    int t = blockIdx.x * blockDim.x + threadIdx.x;
    if (t < NCH) {
        int s = 0;
        int base = t * CH;
        for (int i = 0; i < CH; i++) s += deg[base + i];
        csum[t] = s;
    }
}
__global__ void k_scan_b(const int* __restrict__ csum, int* __restrict__ coff) {
    __shared__ int sc[256];
    int t = threadIdx.x;
    int v[4];
    int part = 0;
#pragma unroll
    for (int q = 0; q < 4; q++) {
        int idx = 4 * t + q;
        v[q] = (idx < NCH) ? csum[idx] : 0;
        part += v[q];
    }
    sc[t] = part;
    __syncthreads();
    for (int off = 1; off < 256; off <<= 1) {
        int add = (t >= off) ? sc[t - off] : 0;
        __syncthreads();
        sc[t] += add;
        __syncthreads();
    }
    int run = sc[t] - part;  // exclusive
#pragma unroll
    for (int q = 0; q < 4; q++) {
        int idx = 4 * t + q;
        if (idx < NCH) coff[idx] = run;
        run += v[q];
    }
}
__global__ void k_scan_c(const int* __restrict__ deg, const int* __restrict__ coff,
                         int* __restrict__ rp) {
    int t = blockIdx.x * blockDim.x + threadIdx.x;
    if (t < NCH) {
        int running = coff[t];
        int base = t * CH;
        for (int i = 0; i < CH; i++) {
            rp[base + i] = running;
            running += deg[base + i];
        }
    }
}

__global__ void k_scatter(const int* __restrict__ idx1, const int* __restrict__ idx2,
                          const int* __restrict__ rp1, int* cur1, int* elist1,
                          int* i1r, int* i2r) {
    for (int e = blockIdx.x * blockDim.x + threadIdx.x; e < NE;
         e += gridDim.x * blockDim.x) {
        int n1 = idx1[e];
        int p = rp1[n1] + atomicAdd(&cur1[n1], 1);
        elist1[p] = e;
        i1r[p] = n1;
        i2r[p] = idx2[e];
    }
}

// ef16p[p][0:48] = pad48(edge_fea[elist1[p]])  (CSR-permuted, f16)
__global__ void k_prep_efg(const float* __restrict__ ef, const int* __restrict__ elist1,
                           f16* __restrict__ ef16p) {
    for (long idx = (long)blockIdx.x * blockDim.x + threadIdx.x; idx < (long)NE * EFW;
         idx += (long)gridDim.x * blockDim.x) {
        long p = idx / EFW;
        int k = (int)(idx - p * EFW);
        int e = elist1[p];
        float v = (k < 41) ? ef[(size_t)e * 41 + k] : 0.f;
        ef16p[idx] = (f16)v;
    }
}

// WTp[slot][k] = Wf_l[k][col(slot)], f16, k padded 169->176.
// slot = 32*g + cl: cl<16 -> gate col 16g+cl ; cl>=16 -> conv col 64+16g+(cl&15)
__global__ void k_wt(const float* __restrict__ Wf_l, f16* __restrict__ WTp) {
    for (int idx = blockIdx.x * blockDim.x + threadIdx.x; idx < 128 * KPAD;
         idx += gridDim.x * blockDim.x) {
        int sl = idx / KPAD, k = idx % KPAD;
        int g = sl >> 5, cl = sl & 31;
        int col = (cl & 16) ? 64 + g * 16 + (cl & 15) : g * 16 + cl;
        float v = (k < 169) ? Wf_l[k * 128 + col] : 0.f;
        WTp[idx] = (f16)v;
    }
}

// ---------- pass A: CSR-ordered GEMM + stats + z store ----------
// One wave per 32-edge tile, all 128 cols via 4 col-groups. B in LDS
// (fragment-major: [s][slot][16 f16] -> ds_read_b128 is 1KB contiguous per
// wave, conflict-free). A-frags (11 x half8) prefetched one tile ahead,
// indices two ahead. No barriers in the main loop.
__global__ __launch_bounds__(256) void k_edge_a(
    const f16* __restrict__ x16, const f16* __restrict__ ef16p,
    const f16* __restrict__ WTp, const int* __restrict__ i1r,
    const int* __restrict__ i2r, float* __restrict__ estats,
    f16* __restrict__ zph) {
    __shared__ f16 ldsB[NFRAG][128][16];  // 44KB
    __shared__ float lst[256];
    int tid = threadIdx.x;
    // cooperative B load: 11*128 = 1408 chunks of 32B = 2816 x 16B
    for (int i = tid; i < NFRAG * 128 * 2; i += 256) {
        int s = i >> 8, rem = i & 255;
        int slot = rem >> 1, half = rem & 1;
        *reinterpret_cast<half8*>(&ldsB[s][slot][half * 8]) =
            *reinterpret_cast<const half8*>(WTp + slot * KPAD + s * 16 + half * 8);
    }
    lst[tid] = 0.f;
    __syncthreads();

    int lane = tid & 63;
    int c = lane & 31, kg = lane >> 5;
    const int zbase = 2 * (c & 15) + ((c >> 4) & 1);  // + 32g per group (f16 units)
    const int ldso = c * 32 + kg * 16;                // lane byte offset in a frag plane

    float s1[4] = {0.f, 0.f, 0.f, 0.f}, s2[4] = {0.f, 0.f, 0.f, 0.f};

    const int NT = NE / 32;
    const int wstride = gridDim.x * 4;
    int t = blockIdx.x * 4 + (tid >> 6);  // wave-global tile id (8192 waves << NT)

    half8 a[NFRAG];
    // prologue: load tile t fully, indices for t+1
    {
        size_t pb = (size_t)t * 32 + c;
        int i1v = i1r[pb], i2v = i2r[pb];
#pragma unroll
        for (int s = 0; s < 4; s++)
            a[s] = *reinterpret_cast<const half8*>(x16 + (size_t)i1v * 64 + s * 16 + kg * 8);
#pragma unroll
        for (int s = 0; s < 4; s++)
            a[4 + s] = *reinterpret_cast<const half8*>(x16 + (size_t)i2v * 64 + s * 16 + kg * 8);
#pragma unroll
        for (int s = 0; s < 3; s++)
            a[8 + s] = __builtin_nontemporal_load(
                reinterpret_cast<const half8*>(ef16p + pb * EFW + s * 16 + kg * 8));
    }
    int tn = t + wstride;
    int i1n = 0, i2n = 0;
    if (tn < NT) {
        i1n = i1r[(size_t)tn * 32 + c];
        i2n = i2r[(size_t)tn * 32 + c];
    }

    while (true) {
        bool hasn = (tn < NT);
        half8 nx[NFRAG];
        int i1nn = 0, i2nn = 0;
        if (hasn) {
#pragma unroll
            for (int s = 0; s < 4; s++)
                nx[s] = *reinterpret_cast<const half8*>(x16 + (size_t)i1n * 64 + s * 16 + kg * 8);
#pragma unroll
            for (int s = 0; s < 4; s++)
                nx[4 + s] = *reinterpret_cast<const half8*>(x16 + (size_t)i2n * 64 + s * 16 + kg * 8);
#pragma unroll
            for (int s = 0; s < 3; s++)
                nx[8 + s] = __builtin_nontemporal_load(reinterpret_cast<const half8*>(
                    ef16p + ((size_t)tn * 32 + c) * EFW + s * 16 + kg * 8));
            int tnn = tn + wstride;
            if (tnn < NT) {
                i1nn = i1r[(size_t)tnn * 32 + c];
                i2nn = i2r[(size_t)tnn * 32 + c];
            }
        }
        // compute tile t: 4 col-groups x 11 MFMA
        int p0 = t * 32;
#pragma unroll
        for (int g = 0; g < 4; g++) {
            f32x16 acc = zero16();
#pragma unroll
            for (int s = 0; s < NFRAG; s++) {
                half8 b = *reinterpret_cast<const half8*>(
                    reinterpret_cast<const char*>(&ldsB[0][0][0]) + s * 4096 + g * 1024 + ldso);
                acc = __builtin_amdgcn_mfma_f32_32x32x16_f16(a[s], b, acc, 0, 0, 0);
            }
#pragma unroll
            for (int r = 0; r < 16; r++) {
                float v = acc[r];
                s1[g] += v;
                s2[g] += v * v;
                int row = (r & 3) + 8 * (r >> 2) + 4 * kg;
                __builtin_nontemporal_store(
                    (f16)v, zph + (size_t)(p0 + row) * 128 + 32 * g + zbase);
            }
        }
        if (!hasn) break;
        t = tn;
        tn += wstride;
#pragma unroll
        for (int s = 0; s < NFRAG; s++) a[s] = nx[s];
        i1n = i1nn;
        i2n = i2nn;
    }
#pragma unroll
    for (int g = 0; g < 4; g++) {
        s1[g] += __shfl_xor(s1[g], 32, 64);
        s2[g] += __shfl_xor(s2[g], 32, 64);
    }
    if (kg == 0) {
#pragma unroll
        for (int g = 0; g < 4; g++) {
            int jz = (c & 16) ? 64 + g * 16 + (c & 15) : g * 16 + c;
            atomicAdd(&lst[jz], s1[g]);
            atomicAdd(&lst[128 + jz], s2[g]);
        }
    }
    __syncthreads();
    atomicAdd(&estats[tid], lst[tid]);
}

// ---------- pass B: wave-per-node reduce (no atomics on nodesum) ----------
__global__ __launch_bounds__(256) void k_nodered(
    const half2v* __restrict__ zp, const int* __restrict__ rp1,
    const int* __restrict__ deg1, const float* __restrict__ estats,
    const float* __restrict__ g1, const float* __restrict__ be1,
    float* __restrict__ raw_out, float* __restrict__ nstats) {
    __shared__ float sstat[128];
    int tid = threadIdx.x;
    int j = tid & 63, wv = tid >> 6;
    if (tid < 128) sstat[tid] = 0.f;
    __syncthreads();
    float mg = estats[j] * (1.f / NE);
    float vg = estats[128 + j] * (1.f / NE) - mg * mg;
    float ag = g1[j] * rsqrtf(vg + EPSB);
    float bg = be1[j] - mg * ag;
    float mc = estats[64 + j] * (1.f / NE);
    float vc = estats[192 + j] * (1.f / NE) - mc * mc;
    float ac = g1[64 + j] * rsqrtf(vc + EPSB);
    float bc = be1[64 + j] - mc * ac;
    float p1 = 0.f, p2 = 0.f;
    for (int n = blockIdx.x * 4 + wv; n < NN; n += gridDim.x * 4) {
        int st = rp1[n], d = deg1[n];
        float acc = 0.f;
#pragma unroll 4
        for (int q = 0; q < d; q++) {
            half2v z = __builtin_nontemporal_load(&zp[(size_t)(st + q) * 64 + j]);
            float g = fsigmoid((float)z[0] * ag + bg);
            float s = fsoftplus((float)z[1] * ac + bc);
            acc += g * s;
        }
        float raw = acc / fmaxf((float)d, 1.f);
        raw_out[(size_t)n * 64 + j] = raw;
        p1 += raw;
        p2 += raw * raw;
    }
    atomicAdd(&sstat[j], p1);
    atomicAdd(&sstat[64 + j], p2);
    __syncthreads();
    if (tid < 128) atomicAdd(&nstats[tid], sstat[tid]);
}

// ---------- node apply: BN2 + softplus (+ crystal pool on last layer) ----------
template <bool LAST>
__global__ __launch_bounds__(256) void k_node_apply(
    const float* __restrict__ raw_in, const float* __restrict__ nstats,
    const float* __restrict__ g2, const float* __restrict__ be2,
    float* __restrict__ xf, f16* __restrict__ x16, const int* __restrict__ idx3,
    float* __restrict__ crsum) {
    for (int idx = blockIdx.x * blockDim.x + threadIdx.x; idx < NN * 64;
         idx += gridDim.x * blockDim.x) {
        int n = idx >> 6, j = idx & 63;
        float m = nstats[j] * (1.f / NN);
        float var = nstats[64 + j] * (1.f / NN) - m * m;
        float rs = rsqrtf(var + EPSB);
        float a = g2[j] * rs;
        float b = be2[j] - m * a;
        float v = fsoftplus(xf[idx] + raw_in[idx] * a + b);
        if (LAST) {
            atomicAdd(&crsum[(size_t)idx3[n] * 64 + j], v);
        } else {
            xf[idx] = v;
            x16[idx] = (f16)v;
        }
    }
}

// ---------- output MLP ----------
__global__ __launch_bounds__(128) void k_out(const float* __restrict__ crsum,
                                             const float* __restrict__ cnt3,
                                             const float* __restrict__ Wc,
                                             const float* __restrict__ bcv,
                                             const float* __restrict__ Wo,
                                             const float* __restrict__ bo,
                                             float* __restrict__ out) {
    __shared__ float crym[64];
    __shared__ float red[4];
    int c = blockIdx.x, tid = threadIdx.x;
    if (tid < 64) crym[tid] = crsum[c * 64 + tid] / fmaxf(cnt3[c], 1.f);
    __syncthreads();
    float hv = bcv[tid];
#pragma unroll
    for (int k = 0; k < 64; k++) hv += crym[k] * Wc[k * 128 + tid];
    hv = fsoftplus(hv);
    float o0 = hv * Wo[tid * 2 + 0];
    float o1 = hv * Wo[tid * 2 + 1];
#pragma unroll
    for (int off = 32; off > 0; off >>= 1) {
        o0 += __shfl_down(o0, off, 64);
        o1 += __shfl_down(o1, off, 64);
    }
    int wv = tid >> 6;
    if ((tid & 63) == 0) { red[wv * 2] = o0; red[wv * 2 + 1] = o1; }
    __syncthreads();
    if (tid == 0) {
        out[c * 2 + 0] = red[0] + red[2] + bo[0];
        out[c * 2 + 1] = red[1] + red[3] + bo[1];
    }
}

// ---------- launch ----------
static inline size_t al256(size_t x) { return (x + 255) & ~(size_t)255; }

extern "C" void kernel_launch(void* const* d_in, const int* in_sizes, int n_in,
                              void* d_out, int out_size, void* d_ws, size_t ws_size,
                              hipStream_t stream) {
    const int* node_fea = (const int*)d_in[0];
    const float* edge_fea = (const float*)d_in[1];
    const int* idx1 = (const int*)d_in[2];
    const int* idx2 = (const int*)d_in[3];
    const int* idx3 = (const int*)d_in[4];
    const float* emb = (const float*)d_in[5];
    const float* Wf = (const float*)d_in[6];
    // d_in[7] = bf: cancels inside training-mode BN, unused.
    const float* g1 = (const float*)d_in[8];
    const float* be1 = (const float*)d_in[9];
    const float* g2 = (const float*)d_in[10];
    const float* be2 = (const float*)d_in[11];
    const float* Wc = (const float*)d_in[12];
    const float* bc = (const float*)d_in[13];
    const float* Wo = (const float*)d_in[14];
    const float* bo = (const float*)d_in[15];
    float* out = (float*)d_out;
    unsigned char* ws = (unsigned char*)d_ws;

    size_t off = 0;
    size_t o_xf = off;     off = al256(off + (size_t)NN * 64 * 4);
    size_t o_x16 = off;    off = al256(off + (size_t)NN * 64 * 2);
    size_t o_efp = off;    off = al256(off + (size_t)NE * EFW * 2);
    size_t o_WT = off;     off = al256(off + (size_t)128 * KPAD * 2);
    size_t o_rp1 = off;    off = al256(off + (size_t)NN * 4);
    size_t o_el1 = off;    off = al256(off + (size_t)NE * 4);
    size_t o_i1r = off;    off = al256(off + (size_t)NE * 4);
    size_t o_i2r = off;    off = al256(off + (size_t)NE * 4);
    size_t o_raw = off;    off = al256(off + (size_t)NN * 64 * 4);
    // prep-zero region (one memset):
    size_t o_deg1 = off;   off = al256(off + (size_t)NN * 4);
    size_t o_cur1 = off;   off = al256(off + (size_t)NN * 4);
    size_t o_cnt3 = off;   off = al256(off + (size_t)NC * 4);
    size_t o_csum = off;   off = al256(off + 1024 * 4);
    size_t o_coff = off;   off = al256(off + 1024 * 4);
    size_t o_crsum = off;  off = al256(off + (size_t)NC * 64 * 4);
    size_t prep_zero_end = off;
    // per-layer-zero region (tiny memset per layer):
    size_t o_estats = off; off = al256(off + 256 * 4);
    size_t o_nstats = off; off = al256(off + 128 * 4);
    size_t layer_zero_end = off;
    size_t o_z = off;      off = al256(off + (size_t)NE * 64 * 4);
    (void)ws_size;

    float* xf = (float*)(ws + o_xf);
    f16* x16 = (f16*)(ws + o_x16);
    f16* ef16p = (f16*)(ws + o_efp);
    f16* WTp = (f16*)(ws + o_WT);
    int* rp1 = (int*)(ws + o_rp1);
    int* elist1 = (int*)(ws + o_el1);
    int* i1r = (int*)(ws + o_i1r);
    int* i2r = (int*)(ws + o_i2r);
    float* raw = (float*)(ws + o_raw);
    int* deg1 = (int*)(ws + o_deg1);
    int* cur1 = (int*)(ws + o_cur1);
    float* cnt3 = (float*)(ws + o_cnt3);
    int* csum = (int*)(ws + o_csum);
    int* coff = (int*)(ws + o_coff);
    float* crsum = (float*)(ws + o_crsum);
    float* estats = (float*)(ws + o_estats);
    float* nstats = (float*)(ws + o_nstats);
    f16* zph = (f16*)(ws + o_z);
    half2v* zp = (half2v*)(ws + o_z);

    hipMemsetAsync(ws + o_deg1, 0, prep_zero_end - o_deg1, stream);
    k_prep_x<<<1024, 256, 0, stream>>>(node_fea, emb, xf, x16);
    k_deg<<<2048, 256, 0, stream>>>(idx1, idx3, deg1, cnt3);
    k_scan_a<<<4, 256, 0, stream>>>(deg1, csum);
    k_scan_b<<<1, 256, 0, stream>>>(csum, coff);
    k_scan_c<<<4, 256, 0, stream>>>(deg1, coff, rp1);
    k_scatter<<<2048, 256, 0, stream>>>(idx1, idx2, rp1, cur1, elist1, i1r, i2r);
    k_prep_efg<<<4096, 256, 0, stream>>>(edge_fea, elist1, ef16p);

    for (int l = 0; l < 3; l++) {
        const float* Wf_l = Wf + (size_t)l * 169 * 128;
        hipMemsetAsync(ws + o_estats, 0, layer_zero_end - o_estats, stream);
        k_wt<<<88, 256, 0, stream>>>(Wf_l, WTp);
        k_edge_a<<<2048, 256, 0, stream>>>(x16, ef16p, WTp, i1r, i2r, estats, zph);
        k_nodered<<<4096, 256, 0, stream>>>(zp, rp1, deg1, estats, g1 + l * 128,
                                            be1 + l * 128, raw, nstats);
        if (l < 2) {
            k_node_apply<false><<<1024, 256, 0, stream>>>(raw, nstats, g2 + l * 64,
                                                          be2 + l * 64, xf, x16,
                                                          idx3, crsum);
        } else {
            k_node_apply<true><<<1024, 256, 0, stream>>>(raw, nstats, g2 + l * 64,
                                                         be2 + l * 64, xf, x16,
                                                         idx3, crsum);
        }
    }
    k_out<<<2000, 128, 0, stream>>>(crsum, cnt3, Wc, bc, Wo, bo, out);
}